// Round 12
// baseline (433.802 us; speedup 1.0000x reference)
//
#include <hip/hip_runtime.h>

#define BATCH 16
#define NNODES 50000
#define NEDGES 1600000
#define BN (BATCH * NNODES)
#define CLAMP_LO -10.0f
#define CLAMP_HI 10.0f
#define EPS_V 1e-6f

// ---------- fused persistent-kernel path ----------
#define GRID2 782                // blocks; also NBINS2 and NBLK2 (1 block = 1 bin = 1 edge slice)
#define BSZ2 64                  // nodes per bin; 782*64 = 50048 >= 50000
#define CAPE2 2560               // per-bin capacity: Poisson(2046) + 11.4 sd
#define EPB2 2048                // edges per block slice; 782*2048 >= NEDGES

// ---------- round-11 fallback path constants ----------
#define NBLK 196
#define EPB 8192
#define BSZ 128
#define NBINS 391
#define CAPE 4992

__device__ __forceinline__ void grid_barrier(int* ctr) {
    __syncthreads();
    if (threadIdx.x == 0) {
        __threadfence();  // agent-scope release: write back XCD L2
        atomicAdd(ctr, 1);
        while (__hip_atomic_load(ctr, __ATOMIC_RELAXED, __HIP_MEMORY_SCOPE_AGENT) < GRID2) {
            __builtin_amdgcn_s_sleep(1);
        }
        __threadfence();  // acquire: invalidate stale cache
    }
    __syncthreads();
}

__global__ __launch_bounds__(256, 4) void fused_all(
    const float* __restrict__ o_pre, const float* __restrict__ E,
    const int* __restrict__ src, const int* __restrict__ dst,
    const float* __restrict__ w, const float* __restrict__ chem,
    const float* __restrict__ threshold, const float* __restrict__ decay,
    float* __restrict__ o_t, uint2* __restrict__ binned,
    int* __restrict__ hist, int* __restrict__ totals, int* __restrict__ bars,
    float* __restrict__ out_o, float* __restrict__ out_e) {
    // LDS: phase-overlaid scratch + persistent E tile
    __shared__ __align__(16) char smem_raw[21264];
    __shared__ float Et_l[BSZ2 * BATCH];  // 4 KB, persists phase 0 -> 4
    int*   lh    = (int*)smem_raw;              // phase 1: 782 ints
    int*   sm    = (int*)smem_raw;              // phase 2: 256 ints
    int*   cur   = (int*)smem_raw;              // phase 3: 782 ints
    uint2* eb    = (uint2*)smem_raw;            // phase 4: 2560 uint2 = 20480 B
    int*   cnt_l = (int*)(smem_raw + 20480);    // 64 ints
    int*   offs  = (int*)(smem_raw + 20736);    // 65 ints
    int*   sc    = (int*)(smem_raw + 20996);    // 64 ints

    const int k = blockIdx.x, tid = threadIdx.x;
    const int node0 = k * BSZ2;
    const int nn = (NNODES - node0 < BSZ2) ? (NNODES - node0) : BSZ2;  // >= 16

    // ---- phase 0+1: transpose slice (o_t global, E tile to LDS) + histogram ----
    for (int i = tid; i < GRID2; i += 256) lh[i] = 0;
    for (int i = tid; i < BSZ2 * BATCH; i += 256) {
        int b = i >> 6, n = i & 63;
        if (n < nn) {
            o_t[(size_t)(node0 + n) * BATCH + b] = o_pre[b * NNODES + node0 + n];
            Et_l[n * BATCH + b] = E[b * NNODES + node0 + n];
        }
    }
    __syncthreads();
    const int4* dst4 = (const int4*)dst;
#pragma unroll
    for (int j = 0; j < 2; ++j) {
        int i4 = k * (EPB2 / 4) + j * 256 + tid;
        if (i4 * 4 < NEDGES) {
            int4 d4 = dst4[i4];
            atomicAdd(&lh[d4.x >> 6], 1);
            atomicAdd(&lh[d4.y >> 6], 1);
            atomicAdd(&lh[d4.z >> 6], 1);
            atomicAdd(&lh[d4.w >> 6], 1);
        }
    }
    __syncthreads();
    for (int i = tid; i < GRID2; i += 256) hist[(size_t)i * GRID2 + k] = lh[i];
    grid_barrier(&bars[0]);

    // ---- phase 2: block k scans bin k's row of 782 block counts ----
    {
        int* row = hist + (size_t)k * GRID2;
        int base = tid * 4;
        int v[4];
        int psum = 0;
#pragma unroll
        for (int j = 0; j < 4; ++j) {
            int idx = base + j;
            v[j] = (idx < GRID2) ? row[idx] : 0;
            psum += v[j];
        }
        sm[tid] = psum;
        __syncthreads();
        for (int off = 1; off < 256; off <<= 1) {
            int a = (tid >= off) ? sm[tid - off] : 0;
            __syncthreads();
            sm[tid] += a;
            __syncthreads();
        }
        int run = (tid > 0) ? sm[tid - 1] : 0;  // exclusive over partials
#pragma unroll
        for (int j = 0; j < 4; ++j) {
            int idx = base + j;
            if (idx < GRID2) { row[idx] = run; run += v[j]; }
        }
        if (tid == 0) totals[k] = sm[255];
    }
    grid_barrier(&bars[1]);

    // ---- phase 3: scatter this block's edge slice into fixed-stride bins ----
    for (int i = tid; i < GRID2; i += 256)
        cur[i] = i * CAPE2 + hist[(size_t)i * GRID2 + k];
    __syncthreads();
    {
        const int4*   src4 = (const int4*)src;
        const float4* w4   = (const float4*)w;
#pragma unroll
        for (int j = 0; j < 2; ++j) {
            int i4 = k * (EPB2 / 4) + j * 256 + tid;
            if (i4 * 4 < NEDGES) {
                int4 d4 = dst4[i4];
                int4 s4 = src4[i4];
                float4 ww = w4[i4];
                int dd[4] = {d4.x, d4.y, d4.z, d4.w};
                int ss[4] = {s4.x, s4.y, s4.z, s4.w};
                float wv[4] = {ww.x, ww.y, ww.z, ww.w};
#pragma unroll
                for (int m = 0; m < 4; ++m) {
                    int d = dd[m];
                    int bin = d >> 6;
                    int pos = atomicAdd(&cur[bin], 1);  // LDS atomic
                    if (pos < (bin + 1) * CAPE2)
                        binned[pos] = make_uint2(
                            (unsigned)ss[m] | ((unsigned)(d & 63) << 16),
                            __float_as_uint(wv[m]));
                }
            }
        }
    }
    grid_barrier(&bars[2]);

    // ---- phase 4: node sub-sort in LDS, register accumulation, epilogue ----
    const int s0 = k * CAPE2;
    int cnt = totals[k];
    if (cnt > CAPE2) cnt = CAPE2;
    const int s1 = s0 + cnt;

    if (tid < BSZ2) cnt_l[tid] = 0;
    __syncthreads();
    for (int i = s0 + tid; i < s1; i += 256)
        atomicAdd(&cnt_l[(binned[i].x >> 16) & 63], 1);
    __syncthreads();
    if (tid < BSZ2) sc[tid] = cnt_l[tid];
    __syncthreads();
    for (int o = 1; o < BSZ2; o <<= 1) {
        int v = (tid >= o && tid < BSZ2) ? sc[tid - o] : 0;
        __syncthreads();
        if (tid < BSZ2) sc[tid] += v;
        __syncthreads();
    }
    if (tid < BSZ2) {
        int ex = sc[tid] - cnt_l[tid];
        offs[tid] = ex;
        cnt_l[tid] = ex;  // cursor
    }
    if (tid == 0) offs[BSZ2] = cnt;
    __syncthreads();
    for (int i = s0 + tid; i < s1; i += 256) {
        uint2 p = binned[i];
        int pos = atomicAdd(&cnt_l[(p.x >> 16) & 63], 1);
        if (pos < CAPE2) eb[pos] = p;
    }
    __syncthreads();

    if (tid < nn * 4) {
        int n = tid >> 2;
        int q = (tid & 3) * 4;
        int gn = node0 + n;
        int e0 = offs[n], e1 = offs[n + 1];
        float4 en = *(const float4*)(Et_l + n * BATCH + q);
        float4 acc = make_float4(0.f, 0.f, 0.f, 0.f);
        for (int i = e0; i < e1; ++i) {
            uint2 p = eb[i];  // quad's 4 lanes: broadcast
            float wv = __uint_as_float(p.y);
            int s = (int)(p.x & 0xFFFFu);
            float4 oj = *(const float4*)(o_t + (size_t)s * BATCH + q);
            acc.x += (oj.x >= en.x) ? oj.x * wv : -oj.x * wv;
            acc.y += (oj.y >= en.y) ? oj.y * wv : -oj.y * wv;
            acc.z += (oj.z >= en.z) ? oj.z * wv : -oj.z * wv;
            acc.w += (oj.w >= en.w) ? oj.w * wv : -oj.w * wv;
        }
        float th = threshold[gn];
        float dc = decay[gn];
        float ev[4] = {en.x, en.y, en.z, en.w};
        float av[4] = {acc.x, acc.y, acc.z, acc.w};
#pragma unroll
        for (int j = 0; j < 4; ++j) {
            int b = q + j;
            float e = ev[j];
            float S = e + chem[b * NNODES + gn] + av[j];
            S = fminf(fmaxf(S, CLAMP_LO), CLAMP_HI);
            float no = fmaxf(S - th, 0.0f);
            float ne;
            if (S > th) ne = no;
            else if (fabsf(S - e) <= EPS_V) ne = e - dc;
            else ne = S;
            out_o[b * NNODES + gn] = no;
            out_e[b * NNODES + gn] = ne;
        }
    }
}

// ================= round-11 fallback chain (validated) =========================

__global__ void prep_hist_kernel(const float* __restrict__ o_pre,
                                 const float* __restrict__ E,
                                 const int* __restrict__ dst,
                                 float* __restrict__ o_t,
                                 float* __restrict__ E_t,
                                 int* __restrict__ hist) {
    __shared__ int lh[NBINS];
    const int tid = threadIdx.x, bid = blockIdx.x;
    for (int i = tid; i < NBINS; i += 256) lh[i] = 0;
    int t = bid * 256 + tid;
    if (t < NNODES) {
        float v[BATCH], u[BATCH];
#pragma unroll
        for (int b = 0; b < BATCH; ++b) {
            v[b] = o_pre[b * NNODES + t];
            u[b] = E[b * NNODES + t];
        }
        float4* op = (float4*)(o_t + (size_t)t * BATCH);
        float4* ep = (float4*)(E_t + (size_t)t * BATCH);
#pragma unroll
        for (int kk = 0; kk < 4; ++kk) {
            op[kk] = make_float4(v[4 * kk], v[4 * kk + 1], v[4 * kk + 2], v[4 * kk + 3]);
            ep[kk] = make_float4(u[4 * kk], u[4 * kk + 1], u[4 * kk + 2], u[4 * kk + 3]);
        }
    }
    __syncthreads();
    const int4* dst4 = (const int4*)dst;
    const int e4base = bid * (EPB / 4);
#pragma unroll
    for (int j = 0; j < 8; ++j) {
        int i4 = e4base + j * 256 + tid;
        if (i4 * 4 < NEDGES) {
            int4 d4 = dst4[i4];
            atomicAdd(&lh[d4.x >> 7], 1);
            atomicAdd(&lh[d4.y >> 7], 1);
            atomicAdd(&lh[d4.z >> 7], 1);
            atomicAdd(&lh[d4.w >> 7], 1);
        }
    }
    __syncthreads();
    for (int i = tid; i < NBINS; i += 256) hist[i * NBLK + bid] = lh[i];
}

__global__ void scanA_kernel(int* __restrict__ hist, int* __restrict__ totals) {
    __shared__ int sm[256];
    int k = blockIdx.x, t = threadIdx.x;
    int v = (t < NBLK) ? hist[k * NBLK + t] : 0;
    sm[t] = v;
    __syncthreads();
    for (int off = 1; off < 256; off <<= 1) {
        int a = (t >= off) ? sm[t - off] : 0;
        __syncthreads();
        sm[t] += a;
        __syncthreads();
    }
    if (t < NBLK) hist[k * NBLK + t] = sm[t] - v;
    if (t == 0) totals[k] = sm[255];
}

__global__ void scatterA_kernel(const int* __restrict__ src,
                                const int* __restrict__ dst,
                                const float* __restrict__ w,
                                const int* __restrict__ hist,
                                uint2* __restrict__ binned) {
    __shared__ int cur[NBINS];
    const int tid = threadIdx.x, bid = blockIdx.x;
    for (int i = tid; i < NBINS; i += 256)
        cur[i] = i * CAPE + hist[i * NBLK + bid];
    __syncthreads();
    const int4*   dst4 = (const int4*)dst;
    const int4*   src4 = (const int4*)src;
    const float4* w4   = (const float4*)w;
    const int e4base = bid * (EPB / 4);
#pragma unroll
    for (int j = 0; j < 8; ++j) {
        int i4 = e4base + j * 256 + tid;
        if (i4 * 4 < NEDGES) {
            int4 d4 = dst4[i4];
            int4 s4 = src4[i4];
            float4 ww = w4[i4];
            int dd[4] = {d4.x, d4.y, d4.z, d4.w};
            int ss[4] = {s4.x, s4.y, s4.z, s4.w};
            float wv[4] = {ww.x, ww.y, ww.z, ww.w};
#pragma unroll
            for (int m = 0; m < 4; ++m) {
                int d = dd[m];
                int bin = d >> 7;
                int pos = atomicAdd(&cur[bin], 1);
                if (pos < (bin + 1) * CAPE)
                    binned[pos] = make_uint2(
                        (unsigned)ss[m] | ((unsigned)(d & 127) << 16),
                        __float_as_uint(wv[m]));
            }
        }
    }
}

__global__ __launch_bounds__(512) void bin_gather2(
    const float* __restrict__ o_t, const float* __restrict__ E_t,
    const float* __restrict__ chem, const float* __restrict__ threshold,
    const float* __restrict__ decay, const int* __restrict__ totals,
    const uint2* __restrict__ binned,
    float* __restrict__ out_o, float* __restrict__ out_e) {
    __shared__ int   cnt_l[BSZ];
    __shared__ int   offs[BSZ + 1];
    __shared__ int   sc[BSZ];
    __shared__ uint2 eb[CAPE];
    const int k = blockIdx.x, tid = threadIdx.x;
    const int node0 = k * BSZ;
    const int nn = (NNODES - node0 < BSZ) ? (NNODES - node0) : BSZ;
    const int s0 = k * CAPE;
    int cnt = totals[k];
    if (cnt > CAPE) cnt = CAPE;
    const int s1 = s0 + cnt;
    if (tid < BSZ) cnt_l[tid] = 0;
    __syncthreads();
    for (int i = s0 + tid; i < s1; i += 512)
        atomicAdd(&cnt_l[(binned[i].x >> 16) & 127], 1);
    __syncthreads();
    if (tid < BSZ) sc[tid] = cnt_l[tid];
    __syncthreads();
    for (int o = 1; o < BSZ; o <<= 1) {
        int v = (tid >= o && tid < BSZ) ? sc[tid - o] : 0;
        __syncthreads();
        if (tid < BSZ) sc[tid] += v;
        __syncthreads();
    }
    if (tid < BSZ) {
        int ex = sc[tid] - cnt_l[tid];
        offs[tid] = ex;
        cnt_l[tid] = ex;
    }
    if (tid == 0) offs[BSZ] = cnt;
    __syncthreads();
    for (int i = s0 + tid; i < s1; i += 512) {
        uint2 p = binned[i];
        int pos = atomicAdd(&cnt_l[(p.x >> 16) & 127], 1);
        if (pos < CAPE) eb[pos] = p;
    }
    __syncthreads();
    for (int t = tid; t < nn * 4; t += 512) {
        int n = t >> 2;
        int q = (t & 3) * 4;
        int gn = node0 + n;
        int e0 = offs[n], e1 = offs[n + 1];
        float4 en = *(const float4*)(E_t + (size_t)gn * BATCH + q);
        float4 acc = make_float4(0.f, 0.f, 0.f, 0.f);
        for (int i = e0; i < e1; ++i) {
            uint2 p = eb[i];
            float wv = __uint_as_float(p.y);
            int s = (int)(p.x & 0xFFFFu);
            float4 oj = *(const float4*)(o_t + (size_t)s * BATCH + q);
            acc.x += (oj.x >= en.x) ? oj.x * wv : -oj.x * wv;
            acc.y += (oj.y >= en.y) ? oj.y * wv : -oj.y * wv;
            acc.z += (oj.z >= en.z) ? oj.z * wv : -oj.z * wv;
            acc.w += (oj.w >= en.w) ? oj.w * wv : -oj.w * wv;
        }
        float th = threshold[gn];
        float dc = decay[gn];
        float ev[4] = {en.x, en.y, en.z, en.w};
        float av[4] = {acc.x, acc.y, acc.z, acc.w};
#pragma unroll
        for (int j = 0; j < 4; ++j) {
            int b = q + j;
            float e = ev[j];
            float S = e + chem[b * NNODES + gn] + av[j];
            S = fminf(fmaxf(S, CLAMP_LO), CLAMP_HI);
            float no = fmaxf(S - th, 0.0f);
            float ne;
            if (S > th) ne = no;
            else if (fabsf(S - e) <= EPS_V) ne = e - dc;
            else ne = S;
            out_o[b * NNODES + gn] = no;
            out_e[b * NNODES + gn] = ne;
        }
    }
}

// ---------- tier-3: device-scope atomic fallback (tiny ws) ----------
__global__ void edge_scatter_dev(const float* __restrict__ o_pre, const float* __restrict__ E,
                                 const float* __restrict__ w, const int* __restrict__ src,
                                 const int* __restrict__ dst, float* __restrict__ gj) {
    int e = blockIdx.x * blockDim.x + threadIdx.x;
    if (e >= NEDGES) return;
    int s = src[e];
    int d = dst[e];
    float wv = w[e];
#pragma unroll
    for (int b = 0; b < BATCH; ++b) {
        float oj = o_pre[b * NNODES + s];
        float en = E[b * NNODES + d];
        atomicAdd(&gj[b * NNODES + d], (oj >= en) ? oj * wv : -oj * wv);
    }
}

__global__ void finalize_dev(const float* __restrict__ chem, const float* __restrict__ E,
                             const float* __restrict__ threshold, const float* __restrict__ decay,
                             float* __restrict__ out_o, float* __restrict__ out_e_gj) {
    int i = blockIdx.x * blockDim.x + threadIdx.x;
    if (i >= BN) return;
    int n = i % NNODES;
    float e = E[i];
    float S = e + chem[i] + out_e_gj[i];
    S = fminf(fmaxf(S, CLAMP_LO), CLAMP_HI);
    float th = threshold[n];
    float no = fmaxf(S - th, 0.0f);
    float ne;
    if (S > th) ne = no;
    else if (fabsf(S - e) <= EPS_V) ne = e - decay[n];
    else ne = S;
    out_o[i] = no;
    out_e_gj[i] = ne;
}

extern "C" void kernel_launch(void* const* d_in, const int* in_sizes, int n_in,
                              void* d_out, int out_size, void* d_ws, size_t ws_size,
                              hipStream_t stream) {
    const float* chem      = (const float*)d_in[0];
    const float* E         = (const float*)d_in[1];
    const float* o_pre     = (const float*)d_in[2];
    const float* w         = (const float*)d_in[3];
    const float* threshold = (const float*)d_in[4];
    const float* decay     = (const float*)d_in[5];
    const int*   src       = (const int*)d_in[6];
    const int*   dst       = (const int*)d_in[7];

    float* out_o = (float*)d_out;
    float* out_e = (float*)d_out + BN;

    // ---- fused layout ----
    const size_t F_OT  = 0;                              // 3,200,000
    const size_t F_BIN = 3200000;                        // 782*2560*8 = 16,015,360
    const size_t F_H   = 19215360;                       // 782*782*4  =  2,446,096
    const size_t F_TOT = 21661456;                       // 782*4
    const size_t F_BAR = 21664592;                       // 3 ints (16-aligned)
    const size_t need_f = F_BAR + 16;

    // ---- round-11 fallback layout ----
    const size_t OT_OFF  = 0;
    const size_t ET_OFF  = 3200000;
    const size_t BIN_OFF = 6400000;
    const size_t H_OFF   = 22014976;
    const size_t TOT_OFF = 22321536;
    const size_t need2   = TOT_OFF + (size_t)NBINS * sizeof(int);

    int blocksPerCU = 0;
    hipError_t oe = hipOccupancyMaxActiveBlocksPerMultiprocessor(&blocksPerCU, fused_all, 256, 0);
    bool coop_ok = (oe == hipSuccess) && ((long)blocksPerCU * 256 >= GRID2) && (ws_size >= need_f);

    if (coop_ok) {
        char* ws = (char*)d_ws;
        float* o_t    = (float*)(ws + F_OT);
        uint2* binned = (uint2*)(ws + F_BIN);
        int*   hist   = (int*)(ws + F_H);
        int*   totals = (int*)(ws + F_TOT);
        int*   bars   = (int*)(ws + F_BAR);
        hipMemsetAsync(bars, 0, 3 * sizeof(int), stream);
        fused_all<<<GRID2, 256, 0, stream>>>(o_pre, E, src, dst, w, chem,
                                             threshold, decay, o_t, binned,
                                             hist, totals, bars, out_o, out_e);
    } else if (ws_size >= need2) {
        char* ws = (char*)d_ws;
        float* o_t    = (float*)(ws + OT_OFF);
        float* E_t    = (float*)(ws + ET_OFF);
        uint2* binned = (uint2*)(ws + BIN_OFF);
        int*   hist   = (int*)(ws + H_OFF);
        int*   totals = (int*)(ws + TOT_OFF);
        prep_hist_kernel<<<NBLK, 256, 0, stream>>>(o_pre, E, dst, o_t, E_t, hist);
        scanA_kernel<<<NBINS, 256, 0, stream>>>(hist, totals);
        scatterA_kernel<<<NBLK, 256, 0, stream>>>(src, dst, w, hist, binned);
        bin_gather2<<<NBINS, 512, 0, stream>>>(o_t, E_t, chem, threshold, decay,
                                               totals, binned, out_o, out_e);
    } else {
        hipMemsetAsync(out_e, 0, (size_t)BN * sizeof(float), stream);
        edge_scatter_dev<<<(NEDGES + 255) / 256, 256, 0, stream>>>(o_pre, E, w, src, dst, out_e);
        finalize_dev<<<(BN + 255) / 256, 256, 0, stream>>>(chem, E, threshold, decay, out_o, out_e);
    }
}

// Round 13
// 140.634 us; speedup vs baseline: 3.0846x; 3.0846x over previous
//
#include <hip/hip_runtime.h>

#define BATCH 16
#define NNODES 50000
#define NEDGES 1600000
#define BN (BATCH * NNODES)
#define CLAMP_LO -10.0f
#define CLAMP_HI 10.0f
#define EPS_V 1e-6f

// ---- geometry ----
#define NBINS 782               // bins of 64 nodes; 782*64 = 50048 >= 50000
#define BSZ 64                  // nodes per bin
#define CAPE 2560               // per-bin capacity: Poisson(2046) + 11.4 sd
#define K1B 250                 // kernel-1 blocks
#define EPB 6400                // edges per k1 block; 250*6400 = 1.6M exact
#define E4PB 1600               // int4s per k1 block
#define NPT 200                 // nodes transposed per k1 block; 250*200 = 50000

// ---- kernel 1: fused transpose + per-slice hist + range-reserve + scatter ----
__global__ __launch_bounds__(256) void prep_scatter(
    const float* __restrict__ o_pre, const float* __restrict__ E,
    const int* __restrict__ src, const int* __restrict__ dst,
    const float* __restrict__ w,
    float* __restrict__ o_t, float* __restrict__ E_t,
    int* __restrict__ cnt,          // global per-bin cursor (memset 0); ends = totals
    uint2* __restrict__ binned) {
    __shared__ int lh[NBINS];       // slice histogram
    __shared__ int cur[NBINS];      // scatter cursors (abs positions)
    const int tid = threadIdx.x, bid = blockIdx.x;

    for (int i = tid; i < NBINS; i += 256) lh[i] = 0;

    // transpose: nodes [bid*200, bid*200+200)
    if (tid < NPT) {
        int t = bid * NPT + tid;
        float v[BATCH], u[BATCH];
#pragma unroll
        for (int b = 0; b < BATCH; ++b) {
            v[b] = o_pre[b * NNODES + t];   // coalesced across t
            u[b] = E[b * NNODES + t];
        }
        float4* op = (float4*)(o_t + (size_t)t * BATCH);
        float4* ep = (float4*)(E_t + (size_t)t * BATCH);
#pragma unroll
        for (int k = 0; k < 4; ++k) {
            op[k] = make_float4(v[4 * k], v[4 * k + 1], v[4 * k + 2], v[4 * k + 3]);
            ep[k] = make_float4(u[4 * k], u[4 * k + 1], u[4 * k + 2], u[4 * k + 3]);
        }
    }
    __syncthreads();  // lh zeroed

    // pass A: histogram this block's 6400-edge slice (int4 loads)
    const int4* dst4 = (const int4*)dst;
    const int i40 = bid * E4PB;
#pragma unroll
    for (int j = 0; j < 7; ++j) {
        int idx = j * 256 + tid;
        if (idx < E4PB) {
            int4 d4 = dst4[i40 + idx];
            atomicAdd(&lh[d4.x >> 6], 1);
            atomicAdd(&lh[d4.y >> 6], 1);
            atomicAdd(&lh[d4.z >> 6], 1);
            atomicAdd(&lh[d4.w >> 6], 1);
        }
    }
    __syncthreads();

    // reserve contiguous ranges: one global atomic per nonzero (block,bin)
    for (int i = tid; i < NBINS; i += 256) {
        int c = lh[i];
        cur[i] = i * CAPE + (c ? atomicAdd(&cnt[i], c) : 0);
    }
    __syncthreads();

    // pass B: scatter the slice (dst re-read hits L2)
    const int4*   src4 = (const int4*)src;
    const float4* w4   = (const float4*)w;
#pragma unroll
    for (int j = 0; j < 7; ++j) {
        int idx = j * 256 + tid;
        if (idx < E4PB) {
            int4 d4 = dst4[i40 + idx];
            int4 s4 = src4[i40 + idx];
            float4 ww = w4[i40 + idx];
            int dd[4] = {d4.x, d4.y, d4.z, d4.w};
            int ss[4] = {s4.x, s4.y, s4.z, s4.w};
            float wv[4] = {ww.x, ww.y, ww.z, ww.w};
#pragma unroll
            for (int m = 0; m < 4; ++m) {
                int d = dd[m];
                int bin = d >> 6;
                int pos = atomicAdd(&cur[bin], 1);       // LDS atomic
                if (pos < (bin + 1) * CAPE)              // overflow guard
                    binned[pos] = make_uint2(
                        (unsigned)ss[m] | ((unsigned)(d & 63) << 16),
                        __float_as_uint(wv[m]));
            }
        }
    }
}

// ---- kernel 2: per-bin node sub-sort in LDS, register accumulation, epilogue ----
__global__ __launch_bounds__(256) void bin_gather2(
    const float* __restrict__ o_t, const float* __restrict__ E_t,
    const float* __restrict__ chem, const float* __restrict__ threshold,
    const float* __restrict__ decay, const int* __restrict__ cnt,
    const uint2* __restrict__ binned,
    float* __restrict__ out_o, float* __restrict__ out_e) {
    __shared__ int   cnt_l[BSZ];
    __shared__ int   offs[BSZ + 1];
    __shared__ int   sc[BSZ];
    __shared__ uint2 eb[CAPE];      // ~20.5 KB

    const int k = blockIdx.x, tid = threadIdx.x;
    const int node0 = k * BSZ;
    const int nn = (NNODES - node0 < BSZ) ? (NNODES - node0) : BSZ;
    const int s0 = k * CAPE;
    int c = cnt[k];
    if (c > CAPE) c = CAPE;
    const int s1 = s0 + c;

    // A1: per-node histogram
    if (tid < BSZ) cnt_l[tid] = 0;
    __syncthreads();
    for (int i = s0 + tid; i < s1; i += 256)
        atomicAdd(&cnt_l[(binned[i].x >> 16) & 63], 1);
    __syncthreads();

    // A2: exclusive scan of 64 counts
    if (tid < BSZ) sc[tid] = cnt_l[tid];
    __syncthreads();
    for (int o = 1; o < BSZ; o <<= 1) {
        int v = (tid >= o && tid < BSZ) ? sc[tid - o] : 0;
        __syncthreads();
        if (tid < BSZ) sc[tid] += v;
        __syncthreads();
    }
    if (tid < BSZ) {
        int ex = sc[tid] - cnt_l[tid];
        offs[tid] = ex;
        cnt_l[tid] = ex;  // cursor
    }
    if (tid == 0) offs[BSZ] = c;
    __syncthreads();

    // A3: scatter into node-sorted LDS array
    for (int i = s0 + tid; i < s1; i += 256) {
        uint2 p = binned[i];
        int pos = atomicAdd(&cnt_l[(p.x >> 16) & 63], 1);
        if (pos < CAPE) eb[pos] = p;
    }
    __syncthreads();

    // B+C: one thread per (node, batch-quad); register accumulation; epilogue
    if (tid < nn * 4) {
        int n = tid >> 2;
        int q = (tid & 3) * 4;
        int gn = node0 + n;
        int e0 = offs[n], e1 = offs[n + 1];
        float4 en = *(const float4*)(E_t + (size_t)gn * BATCH + q);
        float4 acc = make_float4(0.f, 0.f, 0.f, 0.f);
        for (int i = e0; i < e1; ++i) {
            uint2 p = eb[i];  // quad's 4 lanes: same address -> broadcast
            float wv = __uint_as_float(p.y);
            int s = (int)(p.x & 0xFFFFu);
            float4 oj = *(const float4*)(o_t + (size_t)s * BATCH + q);
            acc.x += (oj.x >= en.x) ? oj.x * wv : -oj.x * wv;
            acc.y += (oj.y >= en.y) ? oj.y * wv : -oj.y * wv;
            acc.z += (oj.z >= en.z) ? oj.z * wv : -oj.z * wv;
            acc.w += (oj.w >= en.w) ? oj.w * wv : -oj.w * wv;
        }
        float th = threshold[gn];
        float dc = decay[gn];
        float ev[4] = {en.x, en.y, en.z, en.w};
        float av[4] = {acc.x, acc.y, acc.z, acc.w};
#pragma unroll
        for (int j = 0; j < 4; ++j) {
            int b = q + j;
            float e = ev[j];
            float S = e + chem[b * NNODES + gn] + av[j];
            S = fminf(fmaxf(S, CLAMP_LO), CLAMP_HI);
            float no = fmaxf(S - th, 0.0f);
            float ne;
            if (S > th) ne = no;
            else if (fabsf(S - e) <= EPS_V) ne = e - dc;
            else ne = S;
            out_o[b * NNODES + gn] = no;
            out_e[b * NNODES + gn] = ne;
        }
    }
}

// ---------- fallback: device-scope atomic path (needs no workspace) ----------
__global__ void edge_scatter_dev(const float* __restrict__ o_pre, const float* __restrict__ E,
                                 const float* __restrict__ w, const int* __restrict__ src,
                                 const int* __restrict__ dst, float* __restrict__ gj) {
    int e = blockIdx.x * blockDim.x + threadIdx.x;
    if (e >= NEDGES) return;
    int s = src[e];
    int d = dst[e];
    float wv = w[e];
#pragma unroll
    for (int b = 0; b < BATCH; ++b) {
        float oj = o_pre[b * NNODES + s];
        float en = E[b * NNODES + d];
        atomicAdd(&gj[b * NNODES + d], (oj >= en) ? oj * wv : -oj * wv);
    }
}

__global__ void finalize_dev(const float* __restrict__ chem, const float* __restrict__ E,
                             const float* __restrict__ threshold, const float* __restrict__ decay,
                             float* __restrict__ out_o, float* __restrict__ out_e_gj) {
    int i = blockIdx.x * blockDim.x + threadIdx.x;
    if (i >= BN) return;
    int n = i % NNODES;
    float e = E[i];
    float S = e + chem[i] + out_e_gj[i];
    S = fminf(fmaxf(S, CLAMP_LO), CLAMP_HI);
    float th = threshold[n];
    float no = fmaxf(S - th, 0.0f);
    float ne;
    if (S > th) ne = no;
    else if (fabsf(S - e) <= EPS_V) ne = e - decay[n];
    else ne = S;
    out_o[i] = no;
    out_e_gj[i] = ne;
}

extern "C" void kernel_launch(void* const* d_in, const int* in_sizes, int n_in,
                              void* d_out, int out_size, void* d_ws, size_t ws_size,
                              hipStream_t stream) {
    const float* chem      = (const float*)d_in[0];
    const float* E         = (const float*)d_in[1];
    const float* o_pre     = (const float*)d_in[2];
    const float* w         = (const float*)d_in[3];
    const float* threshold = (const float*)d_in[4];
    const float* decay     = (const float*)d_in[5];
    const int*   src       = (const int*)d_in[6];
    const int*   dst       = (const int*)d_in[7];

    float* out_o = (float*)d_out;
    float* out_e = (float*)d_out + BN;

    // ws layout (bytes, 16B-aligned):
    //   o_t:    [0,          3,200,000)
    //   E_t:    [3,200,000,  6,400,000)
    //   binned: [6,400,000, 22,415,360)   NBINS*CAPE uint2 = 16,015,360
    //   cnt:    [22,415,360, 22,418,488)  NBINS ints
    const size_t OT_OFF  = 0;
    const size_t ET_OFF  = 3200000;
    const size_t BIN_OFF = 6400000;
    const size_t CNT_OFF = 22415360;
    const size_t need    = CNT_OFF + (size_t)NBINS * sizeof(int);

    if (ws_size >= need) {
        char* ws = (char*)d_ws;
        float* o_t    = (float*)(ws + OT_OFF);
        float* E_t    = (float*)(ws + ET_OFF);
        uint2* binned = (uint2*)(ws + BIN_OFF);
        int*   cnt    = (int*)(ws + CNT_OFF);

        hipMemsetAsync(cnt, 0, (size_t)NBINS * sizeof(int), stream);
        prep_scatter<<<K1B, 256, 0, stream>>>(o_pre, E, src, dst, w,
                                              o_t, E_t, cnt, binned);
        bin_gather2<<<NBINS, 256, 0, stream>>>(o_t, E_t, chem, threshold, decay,
                                               cnt, binned, out_o, out_e);
    } else {
        hipMemsetAsync(out_e, 0, (size_t)BN * sizeof(float), stream);
        edge_scatter_dev<<<(NEDGES + 255) / 256, 256, 0, stream>>>(o_pre, E, w, src, dst, out_e);
        finalize_dev<<<(BN + 255) / 256, 256, 0, stream>>>(chem, E, threshold, decay, out_o, out_e);
    }
}